// Round 1
// baseline (3566.467 us; speedup 1.0000x reference)
//
#include <hip/hip_runtime.h>
#include <hip/hip_bf16.h>
#include <math.h>

#define B_    16
#define CI_   256
#define CO_   256
#define H_    64
#define W_    64
#define WDIM_ 512
#define NF_   16
#define FD_   512

// ---------------------------------------------------------------- affine
// s[b,k] = (temb[b,:] . affine_w[k,:]) * (LR_MULT/sqrt(WDIM)) + affine_b[k]*LR_MULT
__global__ __launch_bounds__(256) void affine_kernel(
    const float* __restrict__ temb, const float* __restrict__ affine_w,
    const float* __restrict__ affine_b, float* __restrict__ s_ws) {
  int tid = threadIdx.x;
  int b = tid >> 4, k = tid & 15;
  const float* t = temb + b * WDIM_;
  const float* w = affine_w + k * WDIM_;
  float acc = 0.f;
  for (int j = 0; j < WDIM_; j += 4) {
    float4 tv = *(const float4*)(t + j);
    float4 wv = *(const float4*)(w + j);
    acc += tv.x * wv.x + tv.y * wv.y + tv.z * wv.z + tv.w * wv.w;
  }
  const float WGAIN = 6.9053399e-4f;  // (1/64)/sqrt(512)
  const float LRM   = 1.0f / 64.0f;
  s_ws[tid] = acc * WGAIN + affine_b[k] * LRM;
}

// ---------------------------------------------------------------- mag mix
// mag_ws[b,i,f] = 0.25 * sum_k magnitude[k,i,f] * s[b,k]
__global__ __launch_bounds__(256) void magmix_kernel(
    const float* __restrict__ magnitude, const float* __restrict__ s_ws,
    float* __restrict__ mag_ws) {
  int blk = blockIdx.x;
  int b = blk >> 8, i = blk & 255;
  __shared__ float ssh[NF_];
  if (threadIdx.x < NF_) ssh[threadIdx.x] = s_ws[b * NF_ + threadIdx.x];
  __syncthreads();
  for (int f = threadIdx.x; f < FD_; f += 256) {
    float acc = 0.f;
#pragma unroll
    for (int k = 0; k < NF_; ++k)
      acc += magnitude[(size_t)(k * CI_ + i) * FD_ + f] * ssh[k];
    mag_ws[(size_t)(b * CI_ + i) * FD_ + f] = acc * 0.25f;
  }
}

// ---------------------------------------------------------------- kernel synthesis
// kern_ws[b,o,i,t] = (1/1536) * sum_f basis[i,t,f] * mag_ws[b,i,f] * out_linear[o,f]
__global__ __launch_bounds__(256) void kernsynth_kernel(
    const float* __restrict__ basis, const float* __restrict__ mag_ws,
    const float* __restrict__ out_linear, float* __restrict__ kern_ws) {
  int blk = blockIdx.x;
  int b = blk >> 8, i = blk & 255;
  int tid = threadIdx.x;
  __shared__ float mgs[FD_];
  __shared__ float tl[9 * FD_];
  const float* mg = mag_ws + (size_t)(b * CI_ + i) * FD_;
  mgs[tid] = mg[tid];
  mgs[tid + 256] = mg[tid + 256];
  __syncthreads();
  const float* bs = basis + (size_t)i * 9 * FD_;
  for (int e = tid; e < 9 * FD_; e += 256) tl[e] = bs[e] * mgs[e & (FD_ - 1)];
  __syncthreads();
  int o = tid;
  float acc[9] = {};
  const float* ol = out_linear + (size_t)o * FD_;
  for (int f = 0; f < FD_; f += 4) {
    float4 wf = *(const float4*)(ol + f);
#pragma unroll
    for (int t = 0; t < 9; ++t) {
      float4 tv = *(const float4*)(tl + t * FD_ + f);
      acc[t] += wf.x * tv.x + wf.y * tv.y + wf.z * tv.z + wf.w * tv.w;
    }
  }
  const float KSCALE = 1.0f / 1536.0f;  // FREQ_GAIN * GAIN = (1/32)*(1/48)
  float* kout = kern_ws + ((size_t)(b * CO_ + o) * CI_ + i) * 9;
#pragma unroll
  for (int t = 0; t < 9; ++t) kout[t] = acc[t] * KSCALE;
}

// ---------------------------------------------------------------- grouped conv + silu + bias
// block = (b, 4 consecutive o, 16-row spatial tile); 256 threads, 4 px * 4 o per thread
__global__ __launch_bounds__(256) void conv_kernel(
    const float* __restrict__ x, const float* __restrict__ kern_ws,
    const float* __restrict__ conv_bias, float* __restrict__ out) {
  int bid = blockIdx.x;
  int b = bid >> 8;
  int rem = bid & 255;
  int og = rem >> 2;  // 0..63
  int st = rem & 3;   // 0..3
  int o_base = og * 4;
  int h0 = st * 16;
  int tid = threadIdx.x;

  __shared__ float wk[4 * 2304];
  __shared__ float xs[18 * 66];

  const float* ksrc = kern_ws + (size_t)(b * CO_ + o_base) * 2304;
  for (int e = tid; e < 4 * 2304; e += 256) wk[e] = ksrc[e];

  float acc[4][4] = {};
  const float* xb = x + (size_t)b * CI_ * H_ * W_;

  for (int i = 0; i < CI_; ++i) {
    __syncthreads();
    const float* xc = xb + (size_t)i * H_ * W_;
    for (int e = tid; e < 18 * 66; e += 256) {
      int r = e / 66, c = e - r * 66;
      int gh = h0 + r - 1, gw = c - 1;
      float v = 0.f;
      if ((unsigned)gh < H_ && (unsigned)gw < W_) v = xc[gh * W_ + gw];
      xs[e] = v;
    }
    __syncthreads();
    float w[4][9];
#pragma unroll
    for (int oo = 0; oo < 4; ++oo)
#pragma unroll
      for (int t = 0; t < 9; ++t) w[oo][t] = wk[oo * 2304 + i * 9 + t];
#pragma unroll
    for (int j = 0; j < 4; ++j) {
      int idx = tid + 256 * j;
      int rit = idx >> 6, col = idx & 63;
#pragma unroll
      for (int kh = 0; kh < 3; ++kh)
#pragma unroll
        for (int kw = 0; kw < 3; ++kw) {
          float xv = xs[(rit + kh) * 66 + col + kw];
#pragma unroll
          for (int oo = 0; oo < 4; ++oo) acc[j][oo] += xv * w[oo][kh * 3 + kw];
        }
    }
  }

#pragma unroll
  for (int oo = 0; oo < 4; ++oo) {
    float bias = conv_bias[o_base + oo];
    size_t obase = ((size_t)(b * CO_ + o_base + oo) * H_ + h0) * W_;
#pragma unroll
    for (int j = 0; j < 4; ++j) {
      int idx = tid + 256 * j;
      float y = acc[j][oo];
      float sy = y / (1.f + __expf(-y)) + bias;
      out[obase + idx] = sy;
    }
  }
}

extern "C" void kernel_launch(void* const* d_in, const int* in_sizes, int n_in,
                              void* d_out, int out_size, void* d_ws, size_t ws_size,
                              hipStream_t stream) {
  const float* x          = (const float*)d_in[0];
  const float* temb       = (const float*)d_in[1];
  const float* basis      = (const float*)d_in[2];
  const float* magnitude  = (const float*)d_in[3];
  const float* out_linear = (const float*)d_in[4];
  const float* affine_w   = (const float*)d_in[5];
  const float* affine_b   = (const float*)d_in[6];
  const float* conv_bias  = (const float*)d_in[7];
  float* out = (float*)d_out;

  char* ws = (char*)d_ws;
  float* s_ws    = (float*)ws;                       // 256 floats
  float* mag_ws  = (float*)(ws + 1024);              // 16*256*512 floats = 8 MB
  float* kern_ws = (float*)(ws + 1024 + 8388608);    // 16*256*256*9 floats = 37.7 MB

  affine_kernel<<<1, 256, 0, stream>>>(temb, affine_w, affine_b, s_ws);
  magmix_kernel<<<4096, 256, 0, stream>>>(magnitude, s_ws, mag_ws);
  kernsynth_kernel<<<4096, 256, 0, stream>>>(basis, mag_ws, out_linear, kern_ws);
  conv_kernel<<<4096, 256, 0, stream>>>(x, kern_ws, conv_bias, out);
}

// Round 2
// 715.304 us; speedup vs baseline: 4.9859x; 4.9859x over previous
//
#include <hip/hip_runtime.h>
#include <hip/hip_bf16.h>
#include <math.h>

#define B_    16
#define CI_   256
#define CO_   256
#define H_    64
#define W_    64
#define WDIM_ 512
#define NF_   16
#define FD_   512
#define CIPAD 36

typedef short bf16x8 __attribute__((ext_vector_type(8)));
typedef float f32x4  __attribute__((ext_vector_type(4)));

__device__ __forceinline__ short f2bf(float f) {
  union { float f; unsigned u; } x; x.f = f;
  unsigned r = (x.u + 0x7FFFu + ((x.u >> 16) & 1u)) >> 16;
  return (short)r;
}

// ---------------------------------------------------------------- affine
__global__ __launch_bounds__(256) void affine_kernel(
    const float* __restrict__ temb, const float* __restrict__ affine_w,
    const float* __restrict__ affine_b, float* __restrict__ s_ws) {
  int tid = threadIdx.x;
  int b = tid >> 4, k = tid & 15;
  const float* t = temb + b * WDIM_;
  const float* w = affine_w + k * WDIM_;
  float acc = 0.f;
  for (int j = 0; j < WDIM_; j += 4) {
    float4 tv = *(const float4*)(t + j);
    float4 wv = *(const float4*)(w + j);
    acc += tv.x * wv.x + tv.y * wv.y + tv.z * wv.z + tv.w * wv.w;
  }
  const float WGAIN = 6.9053399e-4f;  // (1/64)/sqrt(512)
  const float LRM   = 1.0f / 64.0f;
  s_ws[tid] = acc * WGAIN + affine_b[k] * LRM;
}

// ---------------------------------------------------------------- mag mix
__global__ __launch_bounds__(256) void magmix_kernel(
    const float* __restrict__ magnitude, const float* __restrict__ s_ws,
    float* __restrict__ mag_ws) {
  int blk = blockIdx.x;
  int b = blk >> 8, i = blk & 255;
  __shared__ float ssh[NF_];
  if (threadIdx.x < NF_) ssh[threadIdx.x] = s_ws[b * NF_ + threadIdx.x];
  __syncthreads();
  for (int f = threadIdx.x; f < FD_; f += 256) {
    float acc = 0.f;
#pragma unroll
    for (int k = 0; k < NF_; ++k)
      acc += magnitude[(size_t)(k * CI_ + i) * FD_ + f] * ssh[k];
    mag_ws[(size_t)(b * CI_ + i) * FD_ + f] = acc * 0.25f;
  }
}

// ---------------------------------------------------------------- kernel synthesis
// writes bf16 kbf[b][t][o][ci]   (ci contiguous)
__global__ __launch_bounds__(256) void kernsynth_kernel(
    const float* __restrict__ basis, const float* __restrict__ mag_ws,
    const float* __restrict__ out_linear, short* __restrict__ kbf) {
  int blk = blockIdx.x;
  int b = blk >> 8, i = blk & 255;
  int tid = threadIdx.x;
  __shared__ float mgs[FD_];
  __shared__ float tl[9 * FD_];
  const float* mg = mag_ws + (size_t)(b * CI_ + i) * FD_;
  mgs[tid] = mg[tid];
  mgs[tid + 256] = mg[tid + 256];
  __syncthreads();
  const float* bs = basis + (size_t)i * 9 * FD_;
  for (int e = tid; e < 9 * FD_; e += 256) tl[e] = bs[e] * mgs[e & (FD_ - 1)];
  __syncthreads();
  int o = tid;
  float acc[9] = {};
  const float* ol = out_linear + (size_t)o * FD_;
  for (int f = 0; f < FD_; f += 4) {
    float4 wf = *(const float4*)(ol + f);
#pragma unroll
    for (int t = 0; t < 9; ++t) {
      float4 tv = *(const float4*)(tl + t * FD_ + f);
      acc[t] += wf.x * tv.x + wf.y * tv.y + wf.z * tv.z + wf.w * tv.w;
    }
  }
  const float KSCALE = 1.0f / 1536.0f;  // FREQ_GAIN * GAIN
#pragma unroll
  for (int t = 0; t < 9; ++t)
    kbf[((size_t)(b * 9 + t) * CO_ + o) * CI_ + i] = f2bf(acc[t] * KSCALE);
}

// ---------------------------------------------------------------- conv via MFMA
// block: (b, 64-o tile, 4-row tile); 4 waves; wave = 64 o x 64 px (one row)
__global__ __launch_bounds__(256) void conv_mfma_kernel(
    const float* __restrict__ x, const short* __restrict__ kbf,
    const float* __restrict__ conv_bias, float* __restrict__ out) {
  int bid = blockIdx.x;
  int b  = bid >> 6;
  int ot = (bid >> 4) & 3;
  int rt = bid & 15;
  int o_base = ot * 64;
  int r0 = rt * 4;
  int tid = threadIdx.x;
  int lane = tid & 63;
  int wv = tid >> 6;
  int orow = lane & 15, kb = lane >> 4;

  __shared__ short as[5 * 64 * CIPAD];   // [t_local][o 64][ci 32 pad 36]
  __shared__ short xs[6 * 66 * CIPAD];   // [row 6][col 66][ci 32 pad 36]

  f32x4 acc[4][4];
#pragma unroll
  for (int m = 0; m < 4; ++m)
#pragma unroll
    for (int n = 0; n < 4; ++n) acc[m][n] = (f32x4)0.f;

  const float* xb = x + (size_t)b * CI_ * H_ * W_;

  for (int cc = 0; cc < 8; ++cc) {
    __syncthreads();  // protect xs/as vs previous reads
    // ---- stage X chunk (32 ci, 6 rows, 66 cols) transposed to [r][c][ci] bf16
    for (int e = tid; e < 32 * 6 * 66; e += 256) {
      int c  = e % 66;
      int cr = e / 66;
      int r  = cr % 6;
      int ci = cr / 6;
      int gh = r0 + r - 1, gw = c - 1;
      float v = 0.f;
      if ((unsigned)gh < (unsigned)H_ && (unsigned)gw < (unsigned)W_)
        v = xb[((size_t)(cc * 32 + ci) * H_ + gh) * W_ + gw];
      xs[(r * 66 + c) * CIPAD + ci] = f2bf(v);
    }
    // ---- stage A taps 0..4
    for (int e = tid; e < 5 * 512; e += 256) {
      int g = e & 7, row = e >> 3;
      int o = row & 63, tl = row >> 6;
      short4 v = *(const short4*)(kbf + (((size_t)(b * 9 + tl) * CO_ + o_base + o) * CI_ + cc * 32 + g * 4));
      *(short4*)(&as[(tl * 64 + o) * CIPAD + g * 4]) = v;
    }
    __syncthreads();

#pragma unroll
    for (int half = 0; half < 2; ++half) {
      int t0 = half ? 5 : 0;
      int Tc = half ? 4 : 5;
      if (half) {
        __syncthreads();  // done reading as for taps 0..4
        for (int e = tid; e < 4 * 512; e += 256) {
          int g = e & 7, row = e >> 3;
          int o = row & 63, tl = row >> 6;
          short4 v = *(const short4*)(kbf + (((size_t)(b * 9 + 5 + tl) * CO_ + o_base + o) * CI_ + cc * 32 + g * 4));
          *(short4*)(&as[(tl * 64 + o) * CIPAD + g * 4]) = v;
        }
        __syncthreads();
      }
      for (int tt = 0; tt < Tc; ++tt) {
        int t = t0 + tt;
        int dh = t / 3 - 1, dw = t % 3 - 1;
        bf16x8 afr[4], bfr[4];
#pragma unroll
        for (int m = 0; m < 4; ++m) {
          const short* p = &as[(tt * 64 + m * 16 + orow) * CIPAD + kb * 8];
          union { bf16x8 v; unsigned long long q[2]; } u;
          u.q[0] = *(const unsigned long long*)p;
          u.q[1] = *(const unsigned long long*)(p + 4);
          afr[m] = u.v;
        }
        int xr = wv + 1 + dh;
#pragma unroll
        for (int n = 0; n < 4; ++n) {
          int xc = n * 16 + orow + 1 + dw;
          const short* p = &xs[(xr * 66 + xc) * CIPAD + kb * 8];
          union { bf16x8 v; unsigned long long q[2]; } u;
          u.q[0] = *(const unsigned long long*)p;
          u.q[1] = *(const unsigned long long*)(p + 4);
          bfr[n] = u.v;
        }
#pragma unroll
        for (int m = 0; m < 4; ++m)
#pragma unroll
          for (int n = 0; n < 4; ++n)
            acc[m][n] = __builtin_amdgcn_mfma_f32_16x16x32_bf16(afr[m], bfr[n], acc[m][n], 0, 0, 0);
      }
    }
  }

  // ---- epilogue: silu + bias
  int row = r0 + wv;
#pragma unroll
  for (int m = 0; m < 4; ++m) {
#pragma unroll
    for (int q = 0; q < 4; ++q) {
      int o = o_base + m * 16 + (lane >> 4) * 4 + q;
      float bias = conv_bias[o];
      size_t obase = (((size_t)b * CO_ + o) * H_ + row) * W_;
#pragma unroll
      for (int n = 0; n < 4; ++n) {
        float y = acc[m][n][q];
        out[obase + n * 16 + (lane & 15)] = y / (1.f + __expf(-y)) + bias;
      }
    }
  }
}

extern "C" void kernel_launch(void* const* d_in, const int* in_sizes, int n_in,
                              void* d_out, int out_size, void* d_ws, size_t ws_size,
                              hipStream_t stream) {
  const float* x          = (const float*)d_in[0];
  const float* temb       = (const float*)d_in[1];
  const float* basis      = (const float*)d_in[2];
  const float* magnitude  = (const float*)d_in[3];
  const float* out_linear = (const float*)d_in[4];
  const float* affine_w   = (const float*)d_in[5];
  const float* affine_b   = (const float*)d_in[6];
  const float* conv_bias  = (const float*)d_in[7];
  float* out = (float*)d_out;

  char* ws = (char*)d_ws;
  float* s_ws   = (float*)ws;                      // 256 floats
  float* mag_ws = (float*)(ws + 1024);             // 8 MB
  short* kbf    = (short*)(ws + 1024 + 8388608);   // 16*9*256*256 bf16 = 18.9 MB

  affine_kernel<<<1, 256, 0, stream>>>(temb, affine_w, affine_b, s_ws);
  magmix_kernel<<<4096, 256, 0, stream>>>(magnitude, s_ws, mag_ws);
  kernsynth_kernel<<<4096, 256, 0, stream>>>(basis, mag_ws, out_linear, kbf);
  conv_mfma_kernel<<<1024, 256, 0, stream>>>(x, kbf, conv_bias, out);
}

// Round 3
// 445.689 us; speedup vs baseline: 8.0021x; 1.6049x over previous
//
#include <hip/hip_runtime.h>
#include <hip/hip_bf16.h>
#include <math.h>

#define B_    16
#define CI_   256
#define CO_   256
#define H_    64
#define W_    64
#define WDIM_ 512
#define NF_   16
#define FD_   512

typedef short bf16x8 __attribute__((ext_vector_type(8)));
typedef short s16x8  __attribute__((ext_vector_type(8)));
typedef float f32x4  __attribute__((ext_vector_type(4)));

__device__ __forceinline__ short f2bf(float f) {
  union { float f; unsigned u; } x; x.f = f;
  unsigned r = (x.u + 0x7FFFu + ((x.u >> 16) & 1u)) >> 16;
  return (short)r;
}

__device__ __forceinline__ void gload16(const short* g, short* l) {
  __builtin_amdgcn_global_load_lds(
      (const __attribute__((address_space(1))) void*)g,
      (__attribute__((address_space(3))) void*)l, 16, 0, 0);
}

// ---------------------------------------------------------------- affine
__global__ __launch_bounds__(256) void affine_kernel(
    const float* __restrict__ temb, const float* __restrict__ affine_w,
    const float* __restrict__ affine_b, float* __restrict__ s_ws) {
  int tid = threadIdx.x;
  int b = tid >> 4, k = tid & 15;
  const float* t = temb + b * WDIM_;
  const float* w = affine_w + k * WDIM_;
  float acc = 0.f;
  for (int j = 0; j < WDIM_; j += 4) {
    float4 tv = *(const float4*)(t + j);
    float4 wv = *(const float4*)(w + j);
    acc += tv.x * wv.x + tv.y * wv.y + tv.z * wv.z + tv.w * wv.w;
  }
  const float WGAIN = 6.9053399e-4f;  // (1/64)/sqrt(512)
  const float LRM   = 1.0f / 64.0f;
  s_ws[tid] = acc * WGAIN + affine_b[k] * LRM;
}

// ---------------------------------------------------------------- mag mix
__global__ __launch_bounds__(256) void magmix_kernel(
    const float* __restrict__ magnitude, const float* __restrict__ s_ws,
    float* __restrict__ mag_ws) {
  int blk = blockIdx.x;
  int b = blk >> 8, i = blk & 255;
  __shared__ float ssh[NF_];
  if (threadIdx.x < NF_) ssh[threadIdx.x] = s_ws[b * NF_ + threadIdx.x];
  __syncthreads();
  for (int f = threadIdx.x; f < FD_; f += 256) {
    float acc = 0.f;
#pragma unroll
    for (int k = 0; k < NF_; ++k)
      acc += magnitude[(size_t)(k * CI_ + i) * FD_ + f] * ssh[k];
    mag_ws[(size_t)(b * CI_ + i) * FD_ + f] = acc * 0.25f;
  }
}

// ---------------------------------------------------------------- kernel synthesis
// writes bf16 kbf[b][t][o][ci]   (ci contiguous)
__global__ __launch_bounds__(256) void kernsynth_kernel(
    const float* __restrict__ basis, const float* __restrict__ mag_ws,
    const float* __restrict__ out_linear, short* __restrict__ kbf) {
  int blk = blockIdx.x;
  int b = blk >> 8, i = blk & 255;
  int tid = threadIdx.x;
  __shared__ float mgs[FD_];
  __shared__ float tl[9 * FD_];
  const float* mg = mag_ws + (size_t)(b * CI_ + i) * FD_;
  mgs[tid] = mg[tid];
  mgs[tid + 256] = mg[tid + 256];
  __syncthreads();
  const float* bs = basis + (size_t)i * 9 * FD_;
  for (int e = tid; e < 9 * FD_; e += 256) tl[e] = bs[e] * mgs[e & (FD_ - 1)];
  __syncthreads();
  int o = tid;
  float acc[9] = {};
  const float* ol = out_linear + (size_t)o * FD_;
  for (int f = 0; f < FD_; f += 4) {
    float4 wf = *(const float4*)(ol + f);
#pragma unroll
    for (int t = 0; t < 9; ++t) {
      float4 tv = *(const float4*)(tl + t * FD_ + f);
      acc[t] += wf.x * tv.x + wf.y * tv.y + wf.z * tv.z + wf.w * tv.w;
    }
  }
  const float KSCALE = 1.0f / 1536.0f;  // FREQ_GAIN * GAIN
#pragma unroll
  for (int t = 0; t < 9; ++t)
    kbf[((size_t)(b * 9 + t) * CO_ + o) * CI_ + i] = f2bf(acc[t] * KSCALE);
}

// ---------------------------------------------------------------- x transpose + pad
// xt[b][hp][wp][ci] bf16, hp/wp in [0,66), zero border
__global__ __launch_bounds__(256) void xpose_kernel(
    const float* __restrict__ x, short* __restrict__ xt) {
  int bid = blockIdx.x;
  int b = bid / 66, hp = bid - b * 66;
  int tid = threadIdx.x;
  short* orow = xt + ((size_t)b * 66 + hp) * 66 * 256;
  if (hp == 0 || hp == 65) {
    s16x8 z = (s16x8)0;
    for (int e = tid; e < 66 * 256 / 8; e += 256) ((s16x8*)orow)[e] = z;
    return;
  }
  int h = hp - 1;
  if (tid < 64) {
    s16x8 z = (s16x8)0;
    int wslot = (tid >> 5) ? 65 : 0;
    ((s16x8*)(orow + wslot * 256))[tid & 31] = z;
  }
  __shared__ float lx[32 * 64];
  const float* xb = x + ((size_t)b * CI_) * H_ * W_ + (size_t)h * W_;
  for (int cc = 0; cc < 8; ++cc) {
    __syncthreads();
    {
      int rr = tid >> 4, c4 = (tid & 15) * 4;
      float4 v0 = *(const float4*)(xb + (size_t)(cc * 32 + rr) * H_ * W_ + c4);
      *(float4*)&lx[rr * 64 + c4] = v0;
      float4 v1 = *(const float4*)(xb + (size_t)(cc * 32 + rr + 16) * H_ * W_ + c4);
      *(float4*)&lx[(rr + 16) * 64 + c4] = v1;
    }
    __syncthreads();
    int w = tid >> 2, ci8 = (tid & 3) * 8;
    s16x8 o8;
#pragma unroll
    for (int k2 = 0; k2 < 8; ++k2) o8[k2] = f2bf(lx[(ci8 + k2) * 64 + w]);
    *(s16x8*)(orow + (size_t)(w + 1) * 256 + cc * 32 + ci8) = o8;
  }
}

// ---------------------------------------------------------------- conv via MFMA
// block: (b, 64-o tile, 4-row tile); 4 waves; wave = 64 o x 64 px (one row)
__global__ __launch_bounds__(256) void conv_mfma_kernel(
    const short* __restrict__ xt, const short* __restrict__ kbf,
    const float* __restrict__ conv_bias, float* __restrict__ out) {
  int bid = blockIdx.x;
  int b  = bid >> 6;
  int ot = (bid >> 4) & 3;
  int rt = bid & 15;
  int o_base = ot * 64;
  int r0 = rt * 4;
  int tid = threadIdx.x;
  int lane = tid & 63;
  int wv = tid >> 6;
  int orow = lane & 15, kb = lane >> 4;

  __shared__ short as_[9 * 64 * 32];   // [t][o 64][ci 32]  36,864 B
  __shared__ short xs[12800];          // [row 6][col 66][ci 32] (+tail) 25,600 B

  f32x4 acc[4][4];
#pragma unroll
  for (int m = 0; m < 4; ++m)
#pragma unroll
    for (int n = 0; n < 4; ++n) acc[m][n] = (f32x4)0.f;

  const short* kb_base = kbf + (size_t)b * 9 * CO_ * CI_;
  const short* xt_b    = xt + (size_t)b * 66 * 66 * 256;
  int l4 = lane >> 2, l16 = (lane & 3) * 8;

  for (int cc = 0; cc < 8; ++cc) {
    __syncthreads();  // all waves done reading previous chunk
    // ---- A: 36 x 1KB chunks; wave wv does [wv*9, wv*9+9)
#pragma unroll
    for (int j = 0; j < 9; ++j) {
      int chunk = wv * 9 + j;
      int row = chunk * 16 + l4;          // 0..575 = t*64+o
      int t = row >> 6, o = row & 63;
      const short* src = kb_base + ((size_t)t * CO_ + o_base + o) * CI_ + cc * 32 + l16;
      gload16(src, &as_[chunk * 512]);
    }
    // ---- X: 25 x 1KB chunks (396 rows of 64B, tail clamped)
    for (int ch = wv; ch < 25; ch += 4) {
      int row = ch * 16 + l4;             // 0..399
      row = row < 396 ? row : 395;
      int r = (row * 1986) >> 17;         // row / 66
      int c = row - r * 66;
      const short* src = xt_b + ((size_t)(r0 + r) * 66 + c) * 256 + cc * 32 + l16;
      gload16(src, &xs[ch * 512]);
    }
    __syncthreads();

#pragma unroll
    for (int t = 0; t < 9; ++t) {
      const int dh = t / 3 - 1, dw = t % 3 - 1;
      bf16x8 afr[4], bfr[4];
#pragma unroll
      for (int m = 0; m < 4; ++m)
        afr[m] = *(const bf16x8*)&as_[(t * 64 + m * 16 + orow) * 32 + kb * 8];
      int xr = wv + 1 + dh;
#pragma unroll
      for (int n = 0; n < 4; ++n) {
        int xc = n * 16 + orow + 1 + dw;
        bfr[n] = *(const bf16x8*)&xs[(xr * 66 + xc) * 32 + kb * 8];
      }
#pragma unroll
      for (int m = 0; m < 4; ++m)
#pragma unroll
        for (int n = 0; n < 4; ++n)
          acc[m][n] = __builtin_amdgcn_mfma_f32_16x16x32_bf16(afr[m], bfr[n], acc[m][n], 0, 0, 0);
    }
  }

  // ---- epilogue: silu + bias
  int row = r0 + wv;
#pragma unroll
  for (int m = 0; m < 4; ++m) {
#pragma unroll
    for (int q = 0; q < 4; ++q) {
      int o = o_base + m * 16 + (lane >> 4) * 4 + q;
      float bias = conv_bias[o];
      size_t obase = (((size_t)b * CO_ + o) * H_ + row) * W_;
#pragma unroll
      for (int n = 0; n < 4; ++n) {
        float y = acc[m][n][q];
        out[obase + n * 16 + (lane & 15)] = y / (1.f + __expf(-y)) + bias;
      }
    }
  }
}

extern "C" void kernel_launch(void* const* d_in, const int* in_sizes, int n_in,
                              void* d_out, int out_size, void* d_ws, size_t ws_size,
                              hipStream_t stream) {
  const float* x          = (const float*)d_in[0];
  const float* temb       = (const float*)d_in[1];
  const float* basis      = (const float*)d_in[2];
  const float* magnitude  = (const float*)d_in[3];
  const float* out_linear = (const float*)d_in[4];
  const float* affine_w   = (const float*)d_in[5];
  const float* affine_b   = (const float*)d_in[6];
  const float* conv_bias  = (const float*)d_in[7];
  float* out = (float*)d_out;

  char* ws = (char*)d_ws;
  float* s_ws = (float*)ws;                          // 1 KB
  short* kbf  = (short*)(ws + 1024);                 // 16*9*256*256 bf16 = 18.9 MB
  short* xt   = (short*)(ws + 1024 + 18874368);      // 16*66*66*256 bf16 = 35.7 MB
  float* mag_ws = (float*)(ws + 1024 + 18874368);    // 8 MB, aliases xt (dead before xpose)

  affine_kernel<<<1, 256, 0, stream>>>(temb, affine_w, affine_b, s_ws);
  magmix_kernel<<<4096, 256, 0, stream>>>(magnitude, s_ws, mag_ws);
  kernsynth_kernel<<<4096, 256, 0, stream>>>(basis, mag_ws, out_linear, kbf);
  xpose_kernel<<<16 * 66, 256, 0, stream>>>(x, xt);
  conv_mfma_kernel<<<1024, 256, 0, stream>>>(xt, kbf, conv_bias, out);
}

// Round 4
// 185.753 us; speedup vs baseline: 19.2001x; 2.3994x over previous
//
#include <hip/hip_runtime.h>
#include <hip/hip_bf16.h>
#include <math.h>

#define B_    16
#define CI_   256
#define CO_   256
#define H_    64
#define W_    64
#define WDIM_ 512
#define NF_   16
#define FD_   512

typedef short bf16x8 __attribute__((ext_vector_type(8)));
typedef short s16x8  __attribute__((ext_vector_type(8)));
typedef float f32x4  __attribute__((ext_vector_type(4)));

__device__ __forceinline__ short f2bf(float f) {
  union { float f; unsigned u; } x; x.f = f;
  unsigned r = (x.u + 0x7FFFu + ((x.u >> 16) & 1u)) >> 16;
  return (short)r;
}

__device__ __forceinline__ void gload16(const short* g, short* l) {
  __builtin_amdgcn_global_load_lds(
      (const __attribute__((address_space(1))) void*)g,
      (__attribute__((address_space(3))) void*)l, 16, 0, 0);
}

// ---------------------------------------------------------------- affine
__global__ __launch_bounds__(256) void affine_kernel(
    const float* __restrict__ temb, const float* __restrict__ affine_w,
    const float* __restrict__ affine_b, float* __restrict__ s_ws) {
  int tid = threadIdx.x;
  int b = tid >> 4, k = tid & 15;
  const float* t = temb + b * WDIM_;
  const float* w = affine_w + k * WDIM_;
  float acc = 0.f;
  for (int j = 0; j < WDIM_; j += 4) {
    float4 tv = *(const float4*)(t + j);
    float4 wv = *(const float4*)(w + j);
    acc += tv.x * wv.x + tv.y * wv.y + tv.z * wv.z + tv.w * wv.w;
  }
  const float WGAIN = 6.9053399e-4f;  // (1/64)/sqrt(512)
  const float LRM   = 1.0f / 64.0f;
  s_ws[tid] = acc * WGAIN + affine_b[k] * LRM;
}

// ---------------------------------------------------------------- mag mix
__global__ __launch_bounds__(256) void magmix_kernel(
    const float* __restrict__ magnitude, const float* __restrict__ s_ws,
    float* __restrict__ mag_ws) {
  int blk = blockIdx.x;
  int b = blk >> 8, i = blk & 255;
  __shared__ float ssh[NF_];
  if (threadIdx.x < NF_) ssh[threadIdx.x] = s_ws[b * NF_ + threadIdx.x];
  __syncthreads();
  for (int f = threadIdx.x; f < FD_; f += 256) {
    float acc = 0.f;
#pragma unroll
    for (int k = 0; k < NF_; ++k)
      acc += magnitude[(size_t)(k * CI_ + i) * FD_ + f] * ssh[k];
    mag_ws[(size_t)(b * CI_ + i) * FD_ + f] = acc * 0.25f;
  }
}

// ---------------------------------------------------------------- kernel synthesis via MFMA
// block = (b, t, i-half): C[i 128][o 256] = sum_f (basis[i,t,f]*mag[b,i,f]) * out_linear[o,f]
// 512 threads = 8 waves (2M x 4N). K-chunk 64. XOR-swizzled LDS.
// writes bf16 kbf[b][t][o][ci]
__global__ __launch_bounds__(512) void kernsynth_mfma_kernel(
    const float* __restrict__ basis, const float* __restrict__ mag_ws,
    const float* __restrict__ out_linear, short* __restrict__ kbf) {
  int bid = blockIdx.x;
  int b  = bid / 18;
  int mt = bid - b * 18;
  int t   = mt >> 1;
  int i0g = (mt & 1) * 128;

  int tid = threadIdx.x;
  int lane = tid & 63;
  int wv = tid >> 6;
  int wm = wv >> 2, wn = wv & 3;
  int l15 = lane & 15, kb = lane >> 4;

  __shared__ short alds[128 * 64];  // 16 KB  [i 128][f 64] swizzled
  __shared__ short blds[256 * 64];  // 32 KB  [o 256][f 64] swizzled

  f32x4 acc[4][4];
#pragma unroll
  for (int m = 0; m < 4; ++m)
#pragma unroll
    for (int n = 0; n < 4; ++n) acc[m][n] = (f32x4)0.f;

  // staging coords
  int ra = tid >> 2;              // A row (i offset), 0..127
  int fsa = (tid & 3) * 16;       // A f-seg base (16 f)
  int rb = tid >> 1;              // B row (o), 0..255
  int fsb = (tid & 1) * 32;       // B f-seg base (32 f)

  const float* bpA = basis + ((size_t)(i0g + ra) * 9 + t) * FD_ + fsa;
  const float* mpA = mag_ws + ((size_t)b * CI_ + i0g + ra) * FD_ + fsa;
  const float* opB = out_linear + (size_t)rb * FD_ + fsb;

  for (int cc = 0; cc < 8; ++cc) {
    int f0 = cc * 64;
    __syncthreads();
    // ---- stage A: tl = basis*mag -> bf16
#pragma unroll
    for (int u = 0; u < 2; ++u) {
      s16x8 pk;
#pragma unroll
      for (int j = 0; j < 2; ++j) {
        float4 b4 = *(const float4*)(bpA + f0 + u * 8 + j * 4);
        float4 m4 = *(const float4*)(mpA + f0 + u * 8 + j * 4);
        pk[j * 4 + 0] = f2bf(b4.x * m4.x);
        pk[j * 4 + 1] = f2bf(b4.y * m4.y);
        pk[j * 4 + 2] = f2bf(b4.z * m4.z);
        pk[j * 4 + 3] = f2bf(b4.w * m4.w);
      }
      int slot = (tid & 3) * 2 + u;
      *(s16x8*)&alds[ra * 64 + ((slot ^ (ra & 7)) << 3)] = pk;
    }
    // ---- stage B: out_linear -> bf16
#pragma unroll
    for (int u = 0; u < 4; ++u) {
      s16x8 pk;
#pragma unroll
      for (int j = 0; j < 2; ++j) {
        float4 o4 = *(const float4*)(opB + f0 + u * 8 + j * 4);
        pk[j * 4 + 0] = f2bf(o4.x);
        pk[j * 4 + 1] = f2bf(o4.y);
        pk[j * 4 + 2] = f2bf(o4.z);
        pk[j * 4 + 3] = f2bf(o4.w);
      }
      int slot = (tid & 1) * 4 + u;
      *(s16x8*)&blds[rb * 64 + ((slot ^ (rb & 7)) << 3)] = pk;
    }
    __syncthreads();

#pragma unroll
    for (int ks = 0; ks < 2; ++ks) {
      bf16x8 afr[4], bfr[4];
#pragma unroll
      for (int m = 0; m < 4; ++m) {
        int row = wm * 64 + m * 16 + l15;
        int slot = ks * 4 + kb;
        afr[m] = *(const bf16x8*)&alds[row * 64 + ((slot ^ (row & 7)) << 3)];
      }
#pragma unroll
      for (int n = 0; n < 4; ++n) {
        int row = wn * 64 + n * 16 + l15;
        int slot = ks * 4 + kb;
        bfr[n] = *(const bf16x8*)&blds[row * 64 + ((slot ^ (row & 7)) << 3)];
      }
#pragma unroll
      for (int m = 0; m < 4; ++m)
#pragma unroll
        for (int n = 0; n < 4; ++n)
          acc[m][n] = __builtin_amdgcn_mfma_f32_16x16x32_bf16(afr[m], bfr[n], acc[m][n], 0, 0, 0);
    }
  }

  // ---- epilogue: scale, pack 4 consecutive i, store 8B
  const float KSCALE = 1.0f / 1536.0f;  // FREQ_GAIN * GAIN
  short* kout = kbf + (size_t)(b * 9 + t) * CO_ * CI_;
#pragma unroll
  for (int m = 0; m < 4; ++m) {
    int i_loc = i0g + wm * 64 + m * 16 + (lane >> 4) * 4;
#pragma unroll
    for (int n = 0; n < 4; ++n) {
      int o = wn * 64 + n * 16 + l15;
      short4 s4;
      s4.x = f2bf(acc[m][n][0] * KSCALE);
      s4.y = f2bf(acc[m][n][1] * KSCALE);
      s4.z = f2bf(acc[m][n][2] * KSCALE);
      s4.w = f2bf(acc[m][n][3] * KSCALE);
      *(short4*)(kout + (size_t)o * CI_ + i_loc) = s4;
    }
  }
}

// ---------------------------------------------------------------- x transpose + pad
// xt[b][hp][wp][ci] bf16, hp/wp in [0,66), zero border
__global__ __launch_bounds__(256) void xpose_kernel(
    const float* __restrict__ x, short* __restrict__ xt) {
  int bid = blockIdx.x;
  int b = bid / 66, hp = bid - b * 66;
  int tid = threadIdx.x;
  short* orow = xt + ((size_t)b * 66 + hp) * 66 * 256;
  if (hp == 0 || hp == 65) {
    s16x8 z = (s16x8)0;
    for (int e = tid; e < 66 * 256 / 8; e += 256) ((s16x8*)orow)[e] = z;
    return;
  }
  int h = hp - 1;
  if (tid < 64) {
    s16x8 z = (s16x8)0;
    int wslot = (tid >> 5) ? 65 : 0;
    ((s16x8*)(orow + wslot * 256))[tid & 31] = z;
  }
  __shared__ float lx[32 * 64];
  const float* xb = x + ((size_t)b * CI_) * H_ * W_ + (size_t)h * W_;
  for (int cc = 0; cc < 8; ++cc) {
    __syncthreads();
    {
      int rr = tid >> 4, c4 = (tid & 15) * 4;
      float4 v0 = *(const float4*)(xb + (size_t)(cc * 32 + rr) * H_ * W_ + c4);
      *(float4*)&lx[rr * 64 + c4] = v0;
      float4 v1 = *(const float4*)(xb + (size_t)(cc * 32 + rr + 16) * H_ * W_ + c4);
      *(float4*)&lx[(rr + 16) * 64 + c4] = v1;
    }
    __syncthreads();
    int w = tid >> 2, ci8 = (tid & 3) * 8;
    s16x8 o8;
#pragma unroll
    for (int k2 = 0; k2 < 8; ++k2) o8[k2] = f2bf(lx[(ci8 + k2) * 64 + w]);
    *(s16x8*)(orow + (size_t)(w + 1) * 256 + cc * 32 + ci8) = o8;
  }
}

// ---------------------------------------------------------------- conv via MFMA
// block: (b, 64-o tile, 4-row tile); 4 waves; wave = 64 o x 64 px (one row)
__global__ __launch_bounds__(256) void conv_mfma_kernel(
    const short* __restrict__ xt, const short* __restrict__ kbf,
    const float* __restrict__ conv_bias, float* __restrict__ out) {
  int bid = blockIdx.x;
  int b  = bid >> 6;
  int ot = (bid >> 4) & 3;
  int rt = bid & 15;
  int o_base = ot * 64;
  int r0 = rt * 4;
  int tid = threadIdx.x;
  int lane = tid & 63;
  int wv = tid >> 6;
  int orow = lane & 15, kb = lane >> 4;

  __shared__ short as_[9 * 64 * 32];   // [t][o 64][ci 32]  36,864 B
  __shared__ short xs[12800];          // [row 6][col 66][ci 32] (+tail) 25,600 B

  f32x4 acc[4][4];
#pragma unroll
  for (int m = 0; m < 4; ++m)
#pragma unroll
    for (int n = 0; n < 4; ++n) acc[m][n] = (f32x4)0.f;

  const short* kb_base = kbf + (size_t)b * 9 * CO_ * CI_;
  const short* xt_b    = xt + (size_t)b * 66 * 66 * 256;
  int l4 = lane >> 2, l16 = (lane & 3) * 8;

  for (int cc = 0; cc < 8; ++cc) {
    __syncthreads();  // all waves done reading previous chunk
    // ---- A: 36 x 1KB chunks; wave wv does [wv*9, wv*9+9)
#pragma unroll
    for (int j = 0; j < 9; ++j) {
      int chunk = wv * 9 + j;
      int row = chunk * 16 + l4;          // 0..575 = t*64+o
      int t = row >> 6, o = row & 63;
      const short* src = kb_base + ((size_t)t * CO_ + o_base + o) * CI_ + cc * 32 + l16;
      gload16(src, &as_[chunk * 512]);
    }
    // ---- X: 25 x 1KB chunks (396 rows of 64B, tail clamped)
    for (int ch = wv; ch < 25; ch += 4) {
      int row = ch * 16 + l4;             // 0..399
      row = row < 396 ? row : 395;
      int r = (row * 1986) >> 17;         // row / 66
      int c = row - r * 66;
      const short* src = xt_b + ((size_t)(r0 + r) * 66 + c) * 256 + cc * 32 + l16;
      gload16(src, &xs[ch * 512]);
    }
    __syncthreads();

#pragma unroll
    for (int t = 0; t < 9; ++t) {
      const int dh = t / 3 - 1, dw = t % 3 - 1;
      bf16x8 afr[4], bfr[4];
#pragma unroll
      for (int m = 0; m < 4; ++m)
        afr[m] = *(const bf16x8*)&as_[(t * 64 + m * 16 + orow) * 32 + kb * 8];
      int xr = wv + 1 + dh;
#pragma unroll
      for (int n = 0; n < 4; ++n) {
        int xc = n * 16 + orow + 1 + dw;
        bfr[n] = *(const bf16x8*)&xs[(xr * 66 + xc) * 32 + kb * 8];
      }
#pragma unroll
      for (int m = 0; m < 4; ++m)
#pragma unroll
        for (int n = 0; n < 4; ++n)
          acc[m][n] = __builtin_amdgcn_mfma_f32_16x16x32_bf16(afr[m], bfr[n], acc[m][n], 0, 0, 0);
    }
  }

  // ---- epilogue: silu + bias
  int row = r0 + wv;
#pragma unroll
  for (int m = 0; m < 4; ++m) {
#pragma unroll
    for (int q = 0; q < 4; ++q) {
      int o = o_base + m * 16 + (lane >> 4) * 4 + q;
      float bias = conv_bias[o];
      size_t obase = (((size_t)b * CO_ + o) * H_ + row) * W_;
#pragma unroll
      for (int n = 0; n < 4; ++n) {
        float y = acc[m][n][q];
        out[obase + n * 16 + (lane & 15)] = y / (1.f + __expf(-y)) + bias;
      }
    }
  }
}

extern "C" void kernel_launch(void* const* d_in, const int* in_sizes, int n_in,
                              void* d_out, int out_size, void* d_ws, size_t ws_size,
                              hipStream_t stream) {
  const float* x          = (const float*)d_in[0];
  const float* temb       = (const float*)d_in[1];
  const float* basis      = (const float*)d_in[2];
  const float* magnitude  = (const float*)d_in[3];
  const float* out_linear = (const float*)d_in[4];
  const float* affine_w   = (const float*)d_in[5];
  const float* affine_b   = (const float*)d_in[6];
  const float* conv_bias  = (const float*)d_in[7];
  float* out = (float*)d_out;

  char* ws = (char*)d_ws;
  float* s_ws = (float*)ws;                          // 1 KB
  short* kbf  = (short*)(ws + 1024);                 // 16*9*256*256 bf16 = 18.9 MB
  short* xt   = (short*)(ws + 1024 + 18874368);      // 16*66*66*256 bf16 = 35.7 MB
  float* mag_ws = (float*)(ws + 1024 + 18874368);    // 8 MB, aliases xt (dead before xpose)

  affine_kernel<<<1, 256, 0, stream>>>(temb, affine_w, affine_b, s_ws);
  magmix_kernel<<<4096, 256, 0, stream>>>(magnitude, s_ws, mag_ws);
  kernsynth_mfma_kernel<<<288, 512, 0, stream>>>(basis, mag_ws, out_linear, kbf);
  xpose_kernel<<<16 * 66, 256, 0, stream>>>(x, xt);
  conv_mfma_kernel<<<1024, 256, 0, stream>>>(xt, kbf, conv_bias, out);
}

// Round 5
// 185.695 us; speedup vs baseline: 19.2060x; 1.0003x over previous
//
#include <hip/hip_runtime.h>
#include <hip/hip_bf16.h>
#include <math.h>

#define B_    16
#define CI_   256
#define CO_   256
#define H_    64
#define W_    64
#define WDIM_ 512
#define NF_   16
#define FD_   512

typedef short bf16x8 __attribute__((ext_vector_type(8)));
typedef short s16x8  __attribute__((ext_vector_type(8)));
typedef float f32x4  __attribute__((ext_vector_type(4)));

__device__ __forceinline__ short f2bf(float f) {
  union { float f; unsigned u; } x; x.f = f;
  unsigned r = (x.u + 0x7FFFu + ((x.u >> 16) & 1u)) >> 16;
  return (short)r;
}

__device__ __forceinline__ void gload16(const short* g, short* l) {
  __builtin_amdgcn_global_load_lds(
      (const __attribute__((address_space(1))) void*)g,
      (__attribute__((address_space(3))) void*)l, 16, 0, 0);
}

// ---------------------------------------------------------------- affine
__global__ __launch_bounds__(256) void affine_kernel(
    const float* __restrict__ temb, const float* __restrict__ affine_w,
    const float* __restrict__ affine_b, float* __restrict__ s_ws) {
  int tid = threadIdx.x;
  int b = tid >> 4, k = tid & 15;
  const float* t = temb + b * WDIM_;
  const float* w = affine_w + k * WDIM_;
  float acc = 0.f;
  for (int j = 0; j < WDIM_; j += 4) {
    float4 tv = *(const float4*)(t + j);
    float4 wv = *(const float4*)(w + j);
    acc += tv.x * wv.x + tv.y * wv.y + tv.z * wv.z + tv.w * wv.w;
  }
  const float WGAIN = 6.9053399e-4f;  // (1/64)/sqrt(512)
  const float LRM   = 1.0f / 64.0f;
  s_ws[tid] = acc * WGAIN + affine_b[k] * LRM;
}

// ---------------------------------------------------------------- mag mix
__global__ __launch_bounds__(256) void magmix_kernel(
    const float* __restrict__ magnitude, const float* __restrict__ s_ws,
    float* __restrict__ mag_ws) {
  int blk = blockIdx.x;
  int b = blk >> 8, i = blk & 255;
  __shared__ float ssh[NF_];
  if (threadIdx.x < NF_) ssh[threadIdx.x] = s_ws[b * NF_ + threadIdx.x];
  __syncthreads();
  for (int f = threadIdx.x; f < FD_; f += 256) {
    float acc = 0.f;
#pragma unroll
    for (int k = 0; k < NF_; ++k)
      acc += magnitude[(size_t)(k * CI_ + i) * FD_ + f] * ssh[k];
    mag_ws[(size_t)(b * CI_ + i) * FD_ + f] = acc * 0.25f;
  }
}

// ---------------------------------------------------------------- kernel synthesis via MFMA
// block = (b, t, i-half): C[i 128][o 256] = sum_f (basis[i,t,f]*mag[b,i,f]) * out_linear[o,f]
__global__ __launch_bounds__(512) void kernsynth_mfma_kernel(
    const float* __restrict__ basis, const float* __restrict__ mag_ws,
    const float* __restrict__ out_linear, short* __restrict__ kbf) {
  int bid = blockIdx.x;
  int b  = bid / 18;
  int mt = bid - b * 18;
  int t   = mt >> 1;
  int i0g = (mt & 1) * 128;

  int tid = threadIdx.x;
  int lane = tid & 63;
  int wv = tid >> 6;
  int wm = wv >> 2, wn = wv & 3;
  int l15 = lane & 15, kb = lane >> 4;

  __shared__ short alds[128 * 64];  // 16 KB  [i 128][f 64] swizzled
  __shared__ short blds[256 * 64];  // 32 KB  [o 256][f 64] swizzled

  f32x4 acc[4][4];
#pragma unroll
  for (int m = 0; m < 4; ++m)
#pragma unroll
    for (int n = 0; n < 4; ++n) acc[m][n] = (f32x4)0.f;

  int ra = tid >> 2;              // A row (i offset), 0..127
  int fsa = (tid & 3) * 16;       // A f-seg base (16 f)
  int rb = tid >> 1;              // B row (o), 0..255
  int fsb = (tid & 1) * 32;       // B f-seg base (32 f)

  const float* bpA = basis + ((size_t)(i0g + ra) * 9 + t) * FD_ + fsa;
  const float* mpA = mag_ws + ((size_t)b * CI_ + i0g + ra) * FD_ + fsa;
  const float* opB = out_linear + (size_t)rb * FD_ + fsb;

  for (int cc = 0; cc < 8; ++cc) {
    int f0 = cc * 64;
    __syncthreads();
#pragma unroll
    for (int u = 0; u < 2; ++u) {
      s16x8 pk;
#pragma unroll
      for (int j = 0; j < 2; ++j) {
        float4 b4 = *(const float4*)(bpA + f0 + u * 8 + j * 4);
        float4 m4 = *(const float4*)(mpA + f0 + u * 8 + j * 4);
        pk[j * 4 + 0] = f2bf(b4.x * m4.x);
        pk[j * 4 + 1] = f2bf(b4.y * m4.y);
        pk[j * 4 + 2] = f2bf(b4.z * m4.z);
        pk[j * 4 + 3] = f2bf(b4.w * m4.w);
      }
      int slot = (tid & 3) * 2 + u;
      *(s16x8*)&alds[ra * 64 + ((slot ^ (ra & 7)) << 3)] = pk;
    }
#pragma unroll
    for (int u = 0; u < 4; ++u) {
      s16x8 pk;
#pragma unroll
      for (int j = 0; j < 2; ++j) {
        float4 o4 = *(const float4*)(opB + f0 + u * 8 + j * 4);
        pk[j * 4 + 0] = f2bf(o4.x);
        pk[j * 4 + 1] = f2bf(o4.y);
        pk[j * 4 + 2] = f2bf(o4.z);
        pk[j * 4 + 3] = f2bf(o4.w);
      }
      int slot = (tid & 1) * 4 + u;
      *(s16x8*)&blds[rb * 64 + ((slot ^ (rb & 7)) << 3)] = pk;
    }
    __syncthreads();

#pragma unroll
    for (int ks = 0; ks < 2; ++ks) {
      bf16x8 afr[4], bfr[4];
#pragma unroll
      for (int m = 0; m < 4; ++m) {
        int row = wm * 64 + m * 16 + l15;
        int slot = ks * 4 + kb;
        afr[m] = *(const bf16x8*)&alds[row * 64 + ((slot ^ (row & 7)) << 3)];
      }
#pragma unroll
      for (int n = 0; n < 4; ++n) {
        int row = wn * 64 + n * 16 + l15;
        int slot = ks * 4 + kb;
        bfr[n] = *(const bf16x8*)&blds[row * 64 + ((slot ^ (row & 7)) << 3)];
      }
#pragma unroll
      for (int m = 0; m < 4; ++m)
#pragma unroll
        for (int n = 0; n < 4; ++n)
          acc[m][n] = __builtin_amdgcn_mfma_f32_16x16x32_bf16(afr[m], bfr[n], acc[m][n], 0, 0, 0);
    }
  }

  const float KSCALE = 1.0f / 1536.0f;  // FREQ_GAIN * GAIN
  short* kout = kbf + (size_t)(b * 9 + t) * CO_ * CI_;
#pragma unroll
  for (int m = 0; m < 4; ++m) {
    int i_loc = i0g + wm * 64 + m * 16 + (lane >> 4) * 4;
#pragma unroll
    for (int n = 0; n < 4; ++n) {
      int o = wn * 64 + n * 16 + l15;
      short4 s4;
      s4.x = f2bf(acc[m][n][0] * KSCALE);
      s4.y = f2bf(acc[m][n][1] * KSCALE);
      s4.z = f2bf(acc[m][n][2] * KSCALE);
      s4.w = f2bf(acc[m][n][3] * KSCALE);
      *(short4*)(kout + (size_t)o * CI_ + i_loc) = s4;
    }
  }
}

// ---------------------------------------------------------------- x transpose + pad
__global__ __launch_bounds__(256) void xpose_kernel(
    const float* __restrict__ x, short* __restrict__ xt) {
  int bid = blockIdx.x;
  int b = bid / 66, hp = bid - b * 66;
  int tid = threadIdx.x;
  short* orow = xt + ((size_t)b * 66 + hp) * 66 * 256;
  if (hp == 0 || hp == 65) {
    s16x8 z = (s16x8)0;
    for (int e = tid; e < 66 * 256 / 8; e += 256) ((s16x8*)orow)[e] = z;
    return;
  }
  int h = hp - 1;
  if (tid < 64) {
    s16x8 z = (s16x8)0;
    int wslot = (tid >> 5) ? 65 : 0;
    ((s16x8*)(orow + wslot * 256))[tid & 31] = z;
  }
  __shared__ float lx[32 * 64];
  const float* xb = x + ((size_t)b * CI_) * H_ * W_ + (size_t)h * W_;
  for (int cc = 0; cc < 8; ++cc) {
    __syncthreads();
    {
      int rr = tid >> 4, c4 = (tid & 15) * 4;
      float4 v0 = *(const float4*)(xb + (size_t)(cc * 32 + rr) * H_ * W_ + c4);
      *(float4*)&lx[rr * 64 + c4] = v0;
      float4 v1 = *(const float4*)(xb + (size_t)(cc * 32 + rr + 16) * H_ * W_ + c4);
      *(float4*)&lx[(rr + 16) * 64 + c4] = v1;
    }
    __syncthreads();
    int w = tid >> 2, ci8 = (tid & 3) * 8;
    s16x8 o8;
#pragma unroll
    for (int k2 = 0; k2 < 8; ++k2) o8[k2] = f2bf(lx[(ci8 + k2) * 64 + w]);
    *(s16x8*)(orow + (size_t)(w + 1) * 256 + cc * 32 + ci8) = o8;
  }
}

// ---------------------------------------------------------------- conv via MFMA
// block: (b, 64-o tile, 4-row tile); 4 waves; wave = 64 o x 64 px (one row)
// LDS rows are 64B (32 ci); 16B slots XOR-swizzled with (row&3):
//   staging pre-swizzles the GLOBAL source (gload_lds dest must stay linear),
//   reads apply the same XOR. 8-way bank conflict -> 2-way (free).
__global__ __launch_bounds__(256) void conv_mfma_kernel(
    const short* __restrict__ xt, const short* __restrict__ kbf,
    const float* __restrict__ conv_bias, float* __restrict__ out) {
  int bid = blockIdx.x;
  int b  = bid >> 6;
  int ot = (bid >> 4) & 3;
  int rt = bid & 15;
  int o_base = ot * 64;
  int r0 = rt * 4;
  int tid = threadIdx.x;
  int lane = tid & 63;
  int wv = tid >> 6;
  int orow = lane & 15, kb = lane >> 4;

  __shared__ short as_[9 * 64 * 32];   // [t][o 64][ci 32]  36,864 B
  __shared__ short xs[12800];          // [row 6][col 66][ci 32] (+tail) 25,600 B

  f32x4 acc[4][4];
#pragma unroll
  for (int m = 0; m < 4; ++m)
#pragma unroll
    for (int n = 0; n < 4; ++n) acc[m][n] = (f32x4)0.f;

  const short* kb_base = kbf + (size_t)b * 9 * CO_ * CI_;
  const short* xt_b    = xt + (size_t)b * 66 * 66 * 256;
  int l4 = lane >> 2;

  for (int cc = 0; cc < 8; ++cc) {
    __syncthreads();  // all waves done reading previous chunk
    // ---- A: 36 x 1KB chunks; wave wv does [wv*9, wv*9+9)
#pragma unroll
    for (int j = 0; j < 9; ++j) {
      int chunk = wv * 9 + j;
      int row = chunk * 16 + l4;          // 0..575 = t*64+o
      int t = row >> 6, o = row & 63;
      int lslot = (lane & 3) ^ (row & 3); // pre-swizzled source slot
      const short* src = kb_base + ((size_t)t * CO_ + o_base + o) * CI_ + cc * 32 + lslot * 8;
      gload16(src, &as_[chunk * 512]);
    }
    // ---- X: 25 x 1KB chunks (396 rows of 64B, tail clamped)
    for (int ch = wv; ch < 25; ch += 4) {
      int row = ch * 16 + l4;             // 0..399
      row = row < 396 ? row : 395;
      int r = (row * 1986) >> 17;         // row / 66
      int c = row - r * 66;
      int lslot = (lane & 3) ^ (row & 3);
      const short* src = xt_b + ((size_t)(r0 + r) * 66 + c) * 256 + cc * 32 + lslot * 8;
      gload16(src, &xs[ch * 512]);
    }
    __syncthreads();

#pragma unroll
    for (int t = 0; t < 9; ++t) {
      const int dh = t / 3 - 1, dw = t % 3 - 1;
      bf16x8 afr[4], bfr[4];
#pragma unroll
      for (int m = 0; m < 4; ++m) {
        int row = t * 64 + m * 16 + orow;
        afr[m] = *(const bf16x8*)&as_[row * 32 + ((kb ^ (row & 3)) << 3)];
      }
      int xr = wv + 1 + dh;
#pragma unroll
      for (int n = 0; n < 4; ++n) {
        int xrow = xr * 66 + n * 16 + orow + 1 + dw;
        bfr[n] = *(const bf16x8*)&xs[xrow * 32 + ((kb ^ (xrow & 3)) << 3)];
      }
#pragma unroll
      for (int m = 0; m < 4; ++m)
#pragma unroll
        for (int n = 0; n < 4; ++n)
          acc[m][n] = __builtin_amdgcn_mfma_f32_16x16x32_bf16(afr[m], bfr[n], acc[m][n], 0, 0, 0);
    }
  }

  // ---- epilogue: silu + bias
  int row = r0 + wv;
#pragma unroll
  for (int m = 0; m < 4; ++m) {
#pragma unroll
    for (int q = 0; q < 4; ++q) {
      int o = o_base + m * 16 + (lane >> 4) * 4 + q;
      float bias = conv_bias[o];
      size_t obase = (((size_t)b * CO_ + o) * H_ + row) * W_;
#pragma unroll
      for (int n = 0; n < 4; ++n) {
        float y = acc[m][n][q];
        out[obase + n * 16 + (lane & 15)] = y / (1.f + __expf(-y)) + bias;
      }
    }
  }
}

extern "C" void kernel_launch(void* const* d_in, const int* in_sizes, int n_in,
                              void* d_out, int out_size, void* d_ws, size_t ws_size,
                              hipStream_t stream) {
  const float* x          = (const float*)d_in[0];
  const float* temb       = (const float*)d_in[1];
  const float* basis      = (const float*)d_in[2];
  const float* magnitude  = (const float*)d_in[3];
  const float* out_linear = (const float*)d_in[4];
  const float* affine_w   = (const float*)d_in[5];
  const float* affine_b   = (const float*)d_in[6];
  const float* conv_bias  = (const float*)d_in[7];
  float* out = (float*)d_out;

  char* ws = (char*)d_ws;
  float* s_ws = (float*)ws;                          // 1 KB
  short* kbf  = (short*)(ws + 1024);                 // 16*9*256*256 bf16 = 18.9 MB
  short* xt   = (short*)(ws + 1024 + 18874368);      // 16*66*66*256 bf16 = 35.7 MB
  float* mag_ws = (float*)(ws + 1024 + 18874368);    // 8 MB, aliases xt (dead before xpose)

  affine_kernel<<<1, 256, 0, stream>>>(temb, affine_w, affine_b, s_ws);
  magmix_kernel<<<4096, 256, 0, stream>>>(magnitude, s_ws, mag_ws);
  kernsynth_mfma_kernel<<<288, 512, 0, stream>>>(basis, mag_ws, out_linear, kbf);
  xpose_kernel<<<16 * 66, 256, 0, stream>>>(x, xt);
  conv_mfma_kernel<<<1024, 256, 0, stream>>>(xt, kbf, conv_bias, out);
}

// Round 6
// 175.644 us; speedup vs baseline: 20.3051x; 1.0572x over previous
//
#include <hip/hip_runtime.h>
#include <hip/hip_bf16.h>
#include <math.h>

#define B_    16
#define CI_   256
#define CO_   256
#define H_    64
#define W_    64
#define WDIM_ 512
#define NF_   16
#define FD_   512

typedef short bf16x8 __attribute__((ext_vector_type(8)));
typedef short s16x8  __attribute__((ext_vector_type(8)));
typedef float f32x4  __attribute__((ext_vector_type(4)));

__device__ __forceinline__ short f2bf(float f) {
  union { float f; unsigned u; } x; x.f = f;
  unsigned r = (x.u + 0x7FFFu + ((x.u >> 16) & 1u)) >> 16;
  return (short)r;
}

__device__ __forceinline__ void gload16(const short* g, short* l) {
  __builtin_amdgcn_global_load_lds(
      (const __attribute__((address_space(1))) void*)g,
      (__attribute__((address_space(3))) void*)l, 16, 0, 0);
}

// Slice-major global layouts (elements):
//   kbf: [b][kb 4][cc 8][t 9][o 256][e 8]
//   xt : [b][kb 4][cc 8][hp 66][wp 66][e 8]
// kb = (ci>>3)&3, cc = ci>>5, e = ci&7  (ci = cc*32 + kb*8 + e)
__device__ __forceinline__ size_t koff(int b, int kb, int cc, int t, int o) {
  return ((((((size_t)b * 4 + kb) * 8 + cc) * 9 + t) * 256) + o) * 8;
}
__device__ __forceinline__ size_t xoff(int b, int kb, int cc, int hp, int wp) {
  return ((((((size_t)b * 4 + kb) * 8 + cc) * 66 + hp) * 66) + wp) * 8;
}

// ---------------------------------------------------------------- affine
__global__ __launch_bounds__(256) void affine_kernel(
    const float* __restrict__ temb, const float* __restrict__ affine_w,
    const float* __restrict__ affine_b, float* __restrict__ s_ws) {
  int tid = threadIdx.x;
  int b = tid >> 4, k = tid & 15;
  const float* t = temb + b * WDIM_;
  const float* w = affine_w + k * WDIM_;
  float acc = 0.f;
  for (int j = 0; j < WDIM_; j += 4) {
    float4 tv = *(const float4*)(t + j);
    float4 wv = *(const float4*)(w + j);
    acc += tv.x * wv.x + tv.y * wv.y + tv.z * wv.z + tv.w * wv.w;
  }
  const float WGAIN = 6.9053399e-4f;  // (1/64)/sqrt(512)
  const float LRM   = 1.0f / 64.0f;
  s_ws[tid] = acc * WGAIN + affine_b[k] * LRM;
}

// ---------------------------------------------------------------- mag mix
__global__ __launch_bounds__(256) void magmix_kernel(
    const float* __restrict__ magnitude, const float* __restrict__ s_ws,
    float* __restrict__ mag_ws) {
  int blk = blockIdx.x;
  int b = blk >> 8, i = blk & 255;
  __shared__ float ssh[NF_];
  if (threadIdx.x < NF_) ssh[threadIdx.x] = s_ws[b * NF_ + threadIdx.x];
  __syncthreads();
  for (int f = threadIdx.x; f < FD_; f += 256) {
    float acc = 0.f;
#pragma unroll
    for (int k = 0; k < NF_; ++k)
      acc += magnitude[(size_t)(k * CI_ + i) * FD_ + f] * ssh[k];
    mag_ws[(size_t)(b * CI_ + i) * FD_ + f] = acc * 0.25f;
  }
}

// ---------------------------------------------------------------- kernel synthesis via MFMA
// block = (b, t, i-half): C[i 128][o 256] = sum_f (basis[i,t,f]*mag[b,i,f]) * out_linear[o,f]
__global__ __launch_bounds__(512) void kernsynth_mfma_kernel(
    const float* __restrict__ basis, const float* __restrict__ mag_ws,
    const float* __restrict__ out_linear, short* __restrict__ kbf) {
  int bid = blockIdx.x;
  int b  = bid / 18;
  int mt = bid - b * 18;
  int t   = mt >> 1;
  int i0g = (mt & 1) * 128;

  int tid = threadIdx.x;
  int lane = tid & 63;
  int wv = tid >> 6;
  int wm = wv >> 2, wn = wv & 3;
  int l15 = lane & 15, kb = lane >> 4;

  __shared__ short alds[128 * 64];  // 16 KB  [i 128][f 64] swizzled
  __shared__ short blds[256 * 64];  // 32 KB  [o 256][f 64] swizzled

  f32x4 acc[4][4];
#pragma unroll
  for (int m = 0; m < 4; ++m)
#pragma unroll
    for (int n = 0; n < 4; ++n) acc[m][n] = (f32x4)0.f;

  int ra = tid >> 2;              // A row (i offset), 0..127
  int fsa = (tid & 3) * 16;       // A f-seg base (16 f)
  int rb = tid >> 1;              // B row (o), 0..255
  int fsb = (tid & 1) * 32;       // B f-seg base (32 f)

  const float* bpA = basis + ((size_t)(i0g + ra) * 9 + t) * FD_ + fsa;
  const float* mpA = mag_ws + ((size_t)b * CI_ + i0g + ra) * FD_ + fsa;
  const float* opB = out_linear + (size_t)rb * FD_ + fsb;

  for (int cc = 0; cc < 8; ++cc) {
    int f0 = cc * 64;
    __syncthreads();
#pragma unroll
    for (int u = 0; u < 2; ++u) {
      s16x8 pk;
#pragma unroll
      for (int j = 0; j < 2; ++j) {
        float4 b4 = *(const float4*)(bpA + f0 + u * 8 + j * 4);
        float4 m4 = *(const float4*)(mpA + f0 + u * 8 + j * 4);
        pk[j * 4 + 0] = f2bf(b4.x * m4.x);
        pk[j * 4 + 1] = f2bf(b4.y * m4.y);
        pk[j * 4 + 2] = f2bf(b4.z * m4.z);
        pk[j * 4 + 3] = f2bf(b4.w * m4.w);
      }
      int slot = (tid & 3) * 2 + u;
      *(s16x8*)&alds[ra * 64 + ((slot ^ (ra & 7)) << 3)] = pk;
    }
#pragma unroll
    for (int u = 0; u < 4; ++u) {
      s16x8 pk;
#pragma unroll
      for (int j = 0; j < 2; ++j) {
        float4 o4 = *(const float4*)(opB + f0 + u * 8 + j * 4);
        pk[j * 4 + 0] = f2bf(o4.x);
        pk[j * 4 + 1] = f2bf(o4.y);
        pk[j * 4 + 2] = f2bf(o4.z);
        pk[j * 4 + 3] = f2bf(o4.w);
      }
      int slot = (tid & 1) * 4 + u;
      *(s16x8*)&blds[rb * 64 + ((slot ^ (rb & 7)) << 3)] = pk;
    }
    __syncthreads();

#pragma unroll
    for (int ks = 0; ks < 2; ++ks) {
      bf16x8 afr[4], bfr[4];
#pragma unroll
      for (int m = 0; m < 4; ++m) {
        int row = wm * 64 + m * 16 + l15;
        int slot = ks * 4 + kb;
        afr[m] = *(const bf16x8*)&alds[row * 64 + ((slot ^ (row & 7)) << 3)];
      }
#pragma unroll
      for (int n = 0; n < 4; ++n) {
        int row = wn * 64 + n * 16 + l15;
        int slot = ks * 4 + kb;
        bfr[n] = *(const bf16x8*)&blds[row * 64 + ((slot ^ (row & 7)) << 3)];
      }
#pragma unroll
      for (int m = 0; m < 4; ++m)
#pragma unroll
        for (int n = 0; n < 4; ++n)
          acc[m][n] = __builtin_amdgcn_mfma_f32_16x16x32_bf16(afr[m], bfr[n], acc[m][n], 0, 0, 0);
    }
  }

  const float KSCALE = 1.0f / 1536.0f;  // FREQ_GAIN * GAIN
#pragma unroll
  for (int m = 0; m < 4; ++m) {
    int i_loc = i0g + wm * 64 + m * 16 + (lane >> 4) * 4;
    int kb2 = (i_loc >> 3) & 3;
    int cc2 = i_loc >> 5;
    int e2  = i_loc & 7;
#pragma unroll
    for (int n = 0; n < 4; ++n) {
      int o = wn * 64 + n * 16 + l15;
      short4 s4;
      s4.x = f2bf(acc[m][n][0] * KSCALE);
      s4.y = f2bf(acc[m][n][1] * KSCALE);
      s4.z = f2bf(acc[m][n][2] * KSCALE);
      s4.w = f2bf(acc[m][n][3] * KSCALE);
      *(short4*)(kbf + koff(b, kb2, cc2, t, o) + e2) = s4;
    }
  }
}

// ---------------------------------------------------------------- x transpose + pad
// writes xt[b][kb][cc][hp][wp][8]
__global__ __launch_bounds__(256) void xpose_kernel(
    const float* __restrict__ x, short* __restrict__ xt) {
  int bid = blockIdx.x;
  int b = bid / 66, hp = bid - b * 66;
  int tid = threadIdx.x;
  s16x8 z = (s16x8)0;
  if (hp == 0 || hp == 65) {
    // zero all 32 slices' row hp
    for (int e = tid; e < 32 * 66; e += 256) {
      int s = e / 66, w = e - s * 66;
      *(s16x8*)(xt + xoff(b, s >> 3, s & 7, hp, w)) = z;
    }
    return;
  }
  int h = hp - 1;
  if (tid < 64) {
    int s = tid >> 1, wslot = (tid & 1) ? 65 : 0;
    *(s16x8*)(xt + xoff(b, s >> 3, s & 7, hp, wslot)) = z;
  }
  __shared__ float lx[32 * 64];
  const float* xb = x + ((size_t)b * CI_) * H_ * W_ + (size_t)h * W_;
  int w = tid >> 2, kb = tid & 3;
  for (int cc = 0; cc < 8; ++cc) {
    __syncthreads();
    {
      int rr = tid >> 4, c4 = (tid & 15) * 4;
      float4 v0 = *(const float4*)(xb + (size_t)(cc * 32 + rr) * H_ * W_ + c4);
      *(float4*)&lx[rr * 64 + c4] = v0;
      float4 v1 = *(const float4*)(xb + (size_t)(cc * 32 + rr + 16) * H_ * W_ + c4);
      *(float4*)&lx[(rr + 16) * 64 + c4] = v1;
    }
    __syncthreads();
    s16x8 o8;
#pragma unroll
    for (int k2 = 0; k2 < 8; ++k2) o8[k2] = f2bf(lx[(kb * 8 + k2) * 64 + w]);
    *(s16x8*)(xt + xoff(b, kb, cc, hp, w + 1)) = o8;
  }
}

// ---------------------------------------------------------------- conv via MFMA
// block: (b, 64-o tile, 4-row tile); 4 waves; wave = 64 o x 64 px (one row).
// LDS is K-slice-major: as_[kb 4][t 9][o 64][16B], xs[kb 4][400 slots][16B].
// Fragment reads: 16 consecutive lanes read 256 contiguous bytes -> conflict-free.
__global__ __launch_bounds__(256) void conv_mfma_kernel(
    const short* __restrict__ xt, const short* __restrict__ kbf,
    const float* __restrict__ conv_bias, float* __restrict__ out) {
  int bid = blockIdx.x;
  int b  = bid >> 6;
  int ot = (bid >> 4) & 3;
  int rt = bid & 15;
  int o_base = ot * 64;
  int r0 = rt * 4;
  int tid = threadIdx.x;
  int lane = tid & 63;
  int wv = tid >> 6;
  int orow = lane & 15, kb = lane >> 4;

  __shared__ short as_[36 * 512];   // 36,864 B  [kb][t][o 64][8]
  __shared__ short xs[25 * 512];    // 25,600 B  [kb][400 px-slots][8]

  f32x4 acc[4][4];
#pragma unroll
  for (int m = 0; m < 4; ++m)
#pragma unroll
    for (int n = 0; n < 4; ++n) acc[m][n] = (f32x4)0.f;

  for (int cc = 0; cc < 8; ++cc) {
    __syncthreads();  // all waves done reading previous chunk
    // ---- A: 36 x 1KB chunks; wave wv stages its own kb-slice (t = j, o = lane)
#pragma unroll
    for (int j = 0; j < 9; ++j) {
      const short* src = kbf + koff(b, wv, cc, j, o_base + lane);
      gload16(src, &as_[(wv * 9 + j) * 512]);
    }
    // ---- X: 25 x 1KB chunks; slice-major, 6400B per kb-slice (400 slots, 396 used)
    for (int ch = wv; ch < 25; ch += 4) {
      int D = ch * 1024 + lane * 16;
      int kb2 = D / 6400;
      int r = (D - kb2 * 6400) >> 4;
      r = r < 396 ? r : 395;
      int xr = (r * 1986) >> 17;   // r / 66
      int c = r - xr * 66;
      const short* src = xt + xoff(b, kb2, cc, r0 + xr, c);
      gload16(src, &xs[ch * 512]);
    }
    __syncthreads();

#pragma unroll
    for (int t = 0; t < 9; ++t) {
      const int dh = t / 3 - 1, dw = t % 3 - 1;
      bf16x8 afr[4], bfr[4];
#pragma unroll
      for (int m = 0; m < 4; ++m)
        afr[m] = *(const bf16x8*)&as_[((kb * 9 + t) * 64 + m * 16 + orow) * 8];
      int xr = wv + 1 + dh;
#pragma unroll
      for (int n = 0; n < 4; ++n) {
        int xc = n * 16 + orow + 1 + dw;
        bfr[n] = *(const bf16x8*)&xs[(kb * 400 + xr * 66 + xc) * 8];
      }
#pragma unroll
      for (int m = 0; m < 4; ++m)
#pragma unroll
        for (int n = 0; n < 4; ++n)
          acc[m][n] = __builtin_amdgcn_mfma_f32_16x16x32_bf16(afr[m], bfr[n], acc[m][n], 0, 0, 0);
    }
  }

  // ---- epilogue: silu + bias
  int row = r0 + wv;
#pragma unroll
  for (int m = 0; m < 4; ++m) {
#pragma unroll
    for (int q = 0; q < 4; ++q) {
      int o = o_base + m * 16 + (lane >> 4) * 4 + q;
      float bias = conv_bias[o];
      size_t obase = (((size_t)b * CO_ + o) * H_ + row) * W_;
#pragma unroll
      for (int n = 0; n < 4; ++n) {
        float y = acc[m][n][q];
        out[obase + n * 16 + (lane & 15)] = y / (1.f + __expf(-y)) + bias;
      }
    }
  }
}

extern "C" void kernel_launch(void* const* d_in, const int* in_sizes, int n_in,
                              void* d_out, int out_size, void* d_ws, size_t ws_size,
                              hipStream_t stream) {
  const float* x          = (const float*)d_in[0];
  const float* temb       = (const float*)d_in[1];
  const float* basis      = (const float*)d_in[2];
  const float* magnitude  = (const float*)d_in[3];
  const float* out_linear = (const float*)d_in[4];
  const float* affine_w   = (const float*)d_in[5];
  const float* affine_b   = (const float*)d_in[6];
  const float* conv_bias  = (const float*)d_in[7];
  float* out = (float*)d_out;

  char* ws = (char*)d_ws;
  float* s_ws = (float*)ws;                          // 1 KB
  short* kbf  = (short*)(ws + 1024);                 // 16*4*8*9*256*8 bf16 = 18.9 MB
  short* xt   = (short*)(ws + 1024 + 18874368);      // 16*4*8*66*66*8 bf16 = 35.7 MB
  float* mag_ws = (float*)(ws + 1024 + 18874368);    // 8 MB, aliases xt (dead before xpose)

  affine_kernel<<<1, 256, 0, stream>>>(temb, affine_w, affine_b, s_ws);
  magmix_kernel<<<4096, 256, 0, stream>>>(magnitude, s_ws, mag_ws);
  kernsynth_mfma_kernel<<<288, 512, 0, stream>>>(basis, mag_ws, out_linear, kbf);
  xpose_kernel<<<16 * 66, 256, 0, stream>>>(x, xt);
  conv_mfma_kernel<<<1024, 256, 0, stream>>>(xt, kbf, conv_bias, out);
}